// Round 1
// baseline (3289.478 us; speedup 1.0000x reference)
//
#include <hip/hip_runtime.h>
#include <cstdint>

#define N_NODES 100000
#define N_EDGES 1600000
#define F_IN 128
#define HID 128
#define N_CLS 40

// ---------------------------------------------------------------------------
// Edge dtype detection: if edge_index is int64, the hi 32-bit words (odd int32
// positions) of the first 256 entries are all zero (values in [0,100000)).
// If int32, those positions are random edge ids — all-zero has prob ~1e-1280.
// Deterministic: same input bytes -> same flag -> same work.
// ---------------------------------------------------------------------------
__global__ __launch_bounds__(256) void k_detect(const int* __restrict__ e, int* __restrict__ flag) {
    __shared__ int sor;
    if (threadIdx.x == 0) sor = 0;
    __syncthreads();
    atomicOr(&sor, e[threadIdx.x * 2 + 1]);
    __syncthreads();
    if (threadIdx.x == 0) flag[0] = (sor == 0) ? 1 : 0;  // 1 = int64 layout
}

__global__ __launch_bounds__(256) void k_cvt(const int* __restrict__ e, const int* __restrict__ flag,
                                             int* __restrict__ s32, int* __restrict__ d32, int E) {
    int i = blockIdx.x * 256 + threadIdx.x;
    if (i >= E) return;
    if (flag[0]) {  // int64 source: lo word at 2*idx
        s32[i] = e[2 * i];
        d32[i] = e[2 * (E + i)];
    } else {
        s32[i] = e[i];
        d32[i] = e[E + i];
    }
}

// deg[i] = (# in-edges) + 1 (self loop); dis = rsqrt(deg)
__global__ __launch_bounds__(256) void k_count(const int* __restrict__ dst, int* __restrict__ cnt, int E) {
    int i = blockIdx.x * 256 + threadIdx.x;
    if (i < E) atomicAdd(&cnt[dst[i]], 1);
}

__global__ __launch_bounds__(256) void k_dis(const int* __restrict__ cnt, float* __restrict__ dis, int N) {
    int i = blockIdx.x * 256 + threadIdx.x;
    if (i < N) dis[i] = rsqrtf((float)(cnt[i] + 1));
}

// ---------------------------------------------------------------------------
// H = X @ W   (X:[N,128], W:[128,OUTC]) — fp32, W fully LDS-resident.
// Block = 256 threads. Thread micro-tile: 8 rows x 4 cols.
//   COLG = OUTC/4 column groups laid along tid%COLG (stride-1 float4 reads of
//   sW rows -> conflict-free); tid/COLG picks the 8-row group; sX reads are
//   wave-broadcast (same address across the col groups of a wave).
// ---------------------------------------------------------------------------
template <int COLG, int ROWS, int OUTC>
__global__ __launch_bounds__(256) void k_gemm(const float* __restrict__ X, const float* __restrict__ W,
                                              float* __restrict__ Hout, int N) {
    __shared__ float sX[ROWS * 128];
    __shared__ float sW[128 * OUTC];
    const int tid  = threadIdx.x;
    const int row0 = blockIdx.x * ROWS;

    for (int i = tid; i < ROWS * 32; i += 256) {  // stage X tile (float4)
        int flat = i * 4;
        int r    = flat >> 7;
        float4 v = make_float4(0.f, 0.f, 0.f, 0.f);
        if (row0 + r < N) v = *(const float4*)(X + (size_t)(row0 + r) * 128 + (flat & 127));
        *(float4*)(sX + flat) = v;
    }
    for (int i = tid; i < 32 * OUTC; i += 256) {  // stage W (float4)
        *(float4*)(sW + i * 4) = *(const float4*)(W + i * 4);
    }
    __syncthreads();

    const int tc = tid % COLG, tr = tid / COLG;
    const int c0 = tc * 4, r0 = tr * 8;
    if (c0 < OUTC) {
        float acc[8][4];
#pragma unroll
        for (int r = 0; r < 8; ++r) acc[r][0] = acc[r][1] = acc[r][2] = acc[r][3] = 0.f;

        for (int k = 0; k < 128; k += 4) {
            float4 wv[4];
#pragma unroll
            for (int j = 0; j < 4; ++j) wv[j] = *(const float4*)(sW + (k + j) * OUTC + c0);
#pragma unroll
            for (int r = 0; r < 8; ++r) {
                float4 xv       = *(const float4*)(sX + (r0 + r) * 128 + k);
                const float* xs = (const float*)&xv;
#pragma unroll
                for (int j = 0; j < 4; ++j) {
                    acc[r][0] = fmaf(xs[j], wv[j].x, acc[r][0]);
                    acc[r][1] = fmaf(xs[j], wv[j].y, acc[r][1]);
                    acc[r][2] = fmaf(xs[j], wv[j].z, acc[r][2]);
                    acc[r][3] = fmaf(xs[j], wv[j].w, acc[r][3]);
                }
            }
        }
#pragma unroll
        for (int r = 0; r < 8; ++r) {
            int row = row0 + r0 + r;
            if (row < N)
                *(float4*)(Hout + (size_t)row * OUTC + c0) =
                    make_float4(acc[r][0], acc[r][1], acc[r][2], acc[r][3]);
        }
    }
}

// A[dst] += dis[src]*dis[dst] * H[src]  over all edges; one wave per edge,
// each lane owns 2 of the 128 features (float2 gather, 2 atomics).
__global__ __launch_bounds__(256) void k_agg128(const int* __restrict__ src, const int* __restrict__ dst,
                                                const float* __restrict__ dis, const float* __restrict__ H,
                                                float* __restrict__ A, int E) {
    int e = blockIdx.x * 4 + (threadIdx.x >> 6);
    if (e >= E) return;
    int   lane = threadIdx.x & 63;
    int   s = src[e], d = dst[e];
    float n  = dis[s] * dis[d];
    float2 v = *(const float2*)(H + (size_t)s * 128 + lane * 2);
    float* a = A + (size_t)d * 128 + lane * 2;
    atomicAdd(a, v.x * n);
    atomicAdd(a + 1, v.y * n);
}

__global__ __launch_bounds__(256) void k_agg40(const int* __restrict__ src, const int* __restrict__ dst,
                                               const float* __restrict__ dis, const float* __restrict__ H,
                                               float* __restrict__ A, int E) {
    int e = blockIdx.x * 4 + (threadIdx.x >> 6);
    if (e >= E) return;
    int lane = threadIdx.x & 63;
    if (lane >= 40) return;
    int   s = src[e], d = dst[e];
    float n = dis[s] * dis[d];
    atomicAdd(A + (size_t)d * 40 + lane, H[(size_t)s * 40 + lane] * n);
}

// A = relu(A + dis^2 * H + bias)   (self-loop term + bias + relu, fused)
__global__ __launch_bounds__(256) void k_epi128(float* __restrict__ A, const float* __restrict__ H,
                                                const float* __restrict__ dis, const float* __restrict__ bias,
                                                int N) {
    int idx = blockIdx.x * 256 + threadIdx.x;  // float4 index
    if (idx >= N * 32) return;
    int   row = idx >> 5;
    int   f4  = idx & 31;
    float d2  = dis[row];
    d2 *= d2;
    float4       a = *(float4*)(A + (size_t)idx * 4);
    const float4 h = *(const float4*)(H + (size_t)idx * 4);
    const float4 b = *(const float4*)(bias + f4 * 4);
    a.x = fmaxf(fmaf(d2, h.x, a.x) + b.x, 0.f);
    a.y = fmaxf(fmaf(d2, h.y, a.y) + b.y, 0.f);
    a.z = fmaxf(fmaf(d2, h.z, a.z) + b.z, 0.f);
    a.w = fmaxf(fmaf(d2, h.w, a.w) + b.w, 0.f);
    *(float4*)(A + (size_t)idx * 4) = a;
}

// out = log_softmax(A + dis^2*H + bias) per row of 40; one wave per row.
__global__ __launch_bounds__(256) void k_lsm(const float* __restrict__ A, const float* __restrict__ H,
                                             const float* __restrict__ dis, const float* __restrict__ bias,
                                             float* __restrict__ out, int N) {
    int row = blockIdx.x * 4 + (threadIdx.x >> 6);
    if (row >= N) return;
    int   lane = threadIdx.x & 63;
    float x = 0.f, m = -3.0e38f;
    if (lane < 40) {
        float d2 = dis[row];
        d2 *= d2;
        x = A[(size_t)row * 40 + lane] + d2 * H[(size_t)row * 40 + lane] + bias[lane];
        m = x;
    }
    for (int off = 32; off; off >>= 1) m = fmaxf(m, __shfl_xor(m, off));
    float s = (lane < 40) ? __expf(x - m) : 0.f;
    for (int off = 32; off; off >>= 1) s += __shfl_xor(s, off);
    float ls = __logf(s);
    if (lane < 40) out[(size_t)row * 40 + lane] = x - m - ls;
}

extern "C" void kernel_launch(void* const* d_in, const int* in_sizes, int n_in,
                              void* d_out, int out_size, void* d_ws, size_t ws_size,
                              hipStream_t stream) {
    const float* x  = (const float*)d_in[0];
    const int*   ei = (const int*)d_in[1];
    const float* W1 = (const float*)d_in[2];
    const float* b1 = (const float*)d_in[3];
    const float* W2 = (const float*)d_in[4];
    const float* b2 = (const float*)d_in[5];
    const float* W3 = (const float*)d_in[6];
    const float* b3 = (const float*)d_in[7];
    float*       out = (float*)d_out;
    const int    N = N_NODES, E = N_EDGES;

    // workspace layout (bytes)
    char*  ws   = (char*)d_ws;
    int*   flag = (int*)ws;                               // 4 B
    int*   cnt  = (int*)(ws + 1024);                      // 400 KB
    float* dis  = (float*)(ws + 512 * 1024);              // 400 KB
    int*   s32  = (int*)(ws + (1u << 20));                // 6.4 MB
    int*   d32  = (int*)(ws + 8 * (1u << 20));            // 6.4 MB
    float* B1   = (float*)(ws + 16 * (1u << 20));         // 51.2 MB (H)
    float* B2   = (float*)(ws + 68 * (1u << 20));         // 51.2 MB (agg)

    // edge dtype detect + normalize to int32
    k_detect<<<1, 256, 0, stream>>>(ei, flag);
    k_cvt<<<(E + 255) / 256, 256, 0, stream>>>(ei, flag, s32, d32, E);

    // degrees
    hipMemsetAsync(cnt, 0, N * sizeof(int), stream);
    k_count<<<(E + 255) / 256, 256, 0, stream>>>(d32, cnt, E);
    k_dis<<<(N + 255) / 256, 256, 0, stream>>>(cnt, dis, N);

    // ---- layer 1 ----
    k_gemm<32, 64, 128><<<(N + 63) / 64, 256, 0, stream>>>(x, W1, B1, N);
    hipMemsetAsync(B2, 0, (size_t)N * 128 * sizeof(float), stream);
    k_agg128<<<(E + 3) / 4, 256, 0, stream>>>(s32, d32, dis, B1, B2, E);
    k_epi128<<<(N * 32 + 255) / 256, 256, 0, stream>>>(B2, B1, dis, b1, N);

    // ---- layer 2 ----
    k_gemm<32, 64, 128><<<(N + 63) / 64, 256, 0, stream>>>(B2, W2, B1, N);
    hipMemsetAsync(B2, 0, (size_t)N * 128 * sizeof(float), stream);
    k_agg128<<<(E + 3) / 4, 256, 0, stream>>>(s32, d32, dis, B1, B2, E);
    k_epi128<<<(N * 32 + 255) / 256, 256, 0, stream>>>(B2, B1, dis, b2, N);

    // ---- layer 3 + log_softmax ----
    k_gemm<16, 128, 40><<<(N + 127) / 128, 256, 0, stream>>>(B2, W3, B1, N);
    hipMemsetAsync(B2, 0, (size_t)N * 40 * sizeof(float), stream);
    k_agg40<<<(E + 3) / 4, 256, 0, stream>>>(s32, d32, dis, B1, B2, E);
    k_lsm<<<(N + 3) / 4, 256, 0, stream>>>(B2, B1, dis, b3, out, N);
}

// Round 2
// 952.083 us; speedup vs baseline: 3.4550x; 3.4550x over previous
//
#include <hip/hip_runtime.h>
#include <cstdint>

#define N_NODES 100000
#define N_EDGES 1600000
#define F_IN 128
#define HID 128
#define N_CLS 40
#define NB_SCAN ((N_NODES + 255) / 256)   // 391 blocks of 256 for the scan

// ---------------------------------------------------------------------------
// Edge dtype detection (int64 vs int32 edge_index) — values < 2^31 so the hi
// words of an int64 layout are all zero. Deterministic.
// ---------------------------------------------------------------------------
__global__ __launch_bounds__(256) void k_detect(const int* __restrict__ e, int* __restrict__ flag) {
    __shared__ int sor;
    if (threadIdx.x == 0) sor = 0;
    __syncthreads();
    atomicOr(&sor, e[threadIdx.x * 2 + 1]);
    __syncthreads();
    if (threadIdx.x == 0) flag[0] = (sor == 0) ? 1 : 0;  // 1 = int64 layout
}

__device__ __forceinline__ int edge_at(const int* e, const int* flag, int which, int i) {
    // which = 0 -> src row, 1 -> dst row
    return flag[0] ? e[2 * ((size_t)which * N_EDGES + i)] : e[(size_t)which * N_EDGES + i];
}

// in-degree count (self-loops added analytically later)
__global__ __launch_bounds__(256) void k_count(const int* __restrict__ e, const int* __restrict__ flag,
                                               int* __restrict__ cnt, int E) {
    int i = blockIdx.x * 256 + threadIdx.x;
    if (i < E) atomicAdd(&cnt[edge_at(e, flag, 1, i)], 1);
}

__global__ __launch_bounds__(256) void k_dis(const int* __restrict__ cnt, float* __restrict__ dis, int N) {
    int i = blockIdx.x * 256 + threadIdx.x;
    if (i < N) dis[i] = rsqrtf((float)(cnt[i] + 1));
}

// ---------------- exclusive scan of cnt[0..N) -> rowptr[0..N] --------------
__global__ __launch_bounds__(256) void k_scan1(const int* __restrict__ cnt, int* __restrict__ part, int N) {
    __shared__ int s[256];
    int i = blockIdx.x * 256 + threadIdx.x;
    s[threadIdx.x] = (i < N) ? cnt[i] : 0;
    __syncthreads();
    for (int off = 128; off; off >>= 1) {
        if (threadIdx.x < off) s[threadIdx.x] += s[threadIdx.x + off];
        __syncthreads();
    }
    if (threadIdx.x == 0) part[blockIdx.x] = s[0];
}

__global__ __launch_bounds__(512) void k_scan2(const int* __restrict__ part, int* __restrict__ part_ex, int nb) {
    __shared__ int s[512];
    int t = threadIdx.x;
    s[t] = (t < nb) ? part[t] : 0;
    __syncthreads();
    for (int off = 1; off < 512; off <<= 1) {
        int v = (t >= off) ? s[t - off] : 0;
        __syncthreads();
        s[t] += v;
        __syncthreads();
    }
    if (t < nb) part_ex[t] = (t == 0) ? 0 : s[t - 1];
}

__global__ __launch_bounds__(256) void k_scan3(const int* __restrict__ cnt, const int* __restrict__ part_ex,
                                               int* __restrict__ rowptr, int N, int E) {
    __shared__ int s[256];
    int i = blockIdx.x * 256 + threadIdx.x;
    int c = (i < N) ? cnt[i] : 0;
    s[threadIdx.x] = c;
    __syncthreads();
    for (int off = 1; off < 256; off <<= 1) {
        int v = (threadIdx.x >= off) ? s[threadIdx.x - off] : 0;
        __syncthreads();
        s[threadIdx.x] += v;
        __syncthreads();
    }
    if (i < N) rowptr[i] = part_ex[blockIdx.x] + s[threadIdx.x] - c;
    if (i == 0) rowptr[N] = E;
}

// counting-sort fill: es[rowptr[dst] + rank] = src
__global__ __launch_bounds__(256) void k_fill(const int* __restrict__ e, const int* __restrict__ flag,
                                              const int* __restrict__ rowptr, int* __restrict__ fill,
                                              int* __restrict__ es, int E) {
    int i = blockIdx.x * 256 + threadIdx.x;
    if (i >= E) return;
    int s = edge_at(e, flag, 0, i);
    int d = edge_at(e, flag, 1, i);
    int pos = rowptr[d] + atomicAdd(&fill[d], 1);
    es[pos] = s;
}

// ---------------------------------------------------------------------------
// Dense transform H = X @ W (fp32, W LDS-resident), unchanged from round 0.
// ---------------------------------------------------------------------------
template <int COLG, int ROWS, int OUTC>
__global__ __launch_bounds__(256) void k_gemm(const float* __restrict__ X, const float* __restrict__ W,
                                              const float* __restrict__ Hout_dummy, float* __restrict__ Hout, int N) {
    __shared__ float sX[ROWS * 128];
    __shared__ float sW[128 * OUTC];
    const int tid  = threadIdx.x;
    const int row0 = blockIdx.x * ROWS;

    for (int i = tid; i < ROWS * 32; i += 256) {
        int flat = i * 4;
        int r    = flat >> 7;
        float4 v = make_float4(0.f, 0.f, 0.f, 0.f);
        if (row0 + r < N) v = *(const float4*)(X + (size_t)(row0 + r) * 128 + (flat & 127));
        *(float4*)(sX + flat) = v;
    }
    for (int i = tid; i < 32 * OUTC; i += 256) {
        *(float4*)(sW + i * 4) = *(const float4*)(W + i * 4);
    }
    __syncthreads();

    const int tc = tid % COLG, tr = tid / COLG;
    const int c0 = tc * 4, r0 = tr * 8;
    if (c0 < OUTC) {
        float acc[8][4];
#pragma unroll
        for (int r = 0; r < 8; ++r) acc[r][0] = acc[r][1] = acc[r][2] = acc[r][3] = 0.f;

        for (int k = 0; k < 128; k += 4) {
            float4 wv[4];
#pragma unroll
            for (int j = 0; j < 4; ++j) wv[j] = *(const float4*)(sW + (k + j) * OUTC + c0);
#pragma unroll
            for (int r = 0; r < 8; ++r) {
                float4 xv       = *(const float4*)(sX + (r0 + r) * 128 + k);
                const float* xs = (const float*)&xv;
#pragma unroll
                for (int j = 0; j < 4; ++j) {
                    acc[r][0] = fmaf(xs[j], wv[j].x, acc[r][0]);
                    acc[r][1] = fmaf(xs[j], wv[j].y, acc[r][1]);
                    acc[r][2] = fmaf(xs[j], wv[j].z, acc[r][2]);
                    acc[r][3] = fmaf(xs[j], wv[j].w, acc[r][3]);
                }
            }
        }
#pragma unroll
        for (int r = 0; r < 8; ++r) {
            int row = row0 + r0 + r;
            if (row < N)
                *(float4*)(Hout + (size_t)row * OUTC + c0) =
                    make_float4(acc[r][0], acc[r][1], acc[r][2], acc[r][3]);
        }
    }
}

// ---------------------------------------------------------------------------
// CSR pull aggregation, 128 features: one wave per dst node, lane owns 2
// features. Self-loop + bias + relu fused. Writes each output exactly once.
// ---------------------------------------------------------------------------
__global__ __launch_bounds__(256) void k_pull128(const int* __restrict__ rowptr, const int* __restrict__ es,
                                                 const float* __restrict__ dis, const float* __restrict__ H,
                                                 const float* __restrict__ bias, float* __restrict__ Out, int N) {
    int node = blockIdx.x * 4 + (threadIdx.x >> 6);
    if (node >= N) return;
    int   lane = threadIdx.x & 63;
    int   beg = rowptr[node], end = rowptr[node + 1];
    float dd  = dis[node];

    float2 hv  = *(const float2*)(H + (size_t)node * 128 + lane * 2);
    float2 acc = make_float2(dd * dd * hv.x, dd * dd * hv.y);

    for (int p = beg; p < end; ++p) {
        int    s = es[p];               // wave-uniform broadcast read
        float  n = dis[s] * dd;
        float2 v = *(const float2*)(H + (size_t)s * 128 + lane * 2);
        acc.x = fmaf(v.x, n, acc.x);
        acc.y = fmaf(v.y, n, acc.y);
    }
    float2 b = *(const float2*)(bias + lane * 2);
    acc.x = fmaxf(acc.x + b.x, 0.f);
    acc.y = fmaxf(acc.y + b.y, 0.f);
    *(float2*)(Out + (size_t)node * 128 + lane * 2) = acc;
}

// 40-feature pull + bias + log_softmax, one wave per node (lanes 0..39 active
// for data, full wave participates in shuffles).
__global__ __launch_bounds__(256) void k_pull40_lsm(const int* __restrict__ rowptr, const int* __restrict__ es,
                                                    const float* __restrict__ dis, const float* __restrict__ H,
                                                    const float* __restrict__ bias, float* __restrict__ out, int N) {
    int node = blockIdx.x * 4 + (threadIdx.x >> 6);
    if (node >= N) return;
    int   lane = threadIdx.x & 63;
    int   beg = rowptr[node], end = rowptr[node + 1];
    float dd  = dis[node];

    float acc = 0.f;
    if (lane < 40) acc = dd * dd * H[(size_t)node * 40 + lane];
    for (int p = beg; p < end; ++p) {
        int   s = es[p];
        float n = dis[s] * dd;
        if (lane < 40) acc = fmaf(H[(size_t)s * 40 + lane], n, acc);
    }
    float x = 0.f, m = -3.0e38f;
    if (lane < 40) { x = acc + bias[lane]; m = x; }
    for (int off = 32; off; off >>= 1) m = fmaxf(m, __shfl_xor(m, off));
    float sum = (lane < 40) ? __expf(x - m) : 0.f;
    for (int off = 32; off; off >>= 1) sum += __shfl_xor(sum, off);
    float ls = __logf(sum);
    if (lane < 40) out[(size_t)node * 40 + lane] = x - m - ls;
}

extern "C" void kernel_launch(void* const* d_in, const int* in_sizes, int n_in,
                              void* d_out, int out_size, void* d_ws, size_t ws_size,
                              hipStream_t stream) {
    const float* x   = (const float*)d_in[0];
    const int*   ei  = (const int*)d_in[1];
    const float* W1  = (const float*)d_in[2];
    const float* b1  = (const float*)d_in[3];
    const float* W2  = (const float*)d_in[4];
    const float* b2  = (const float*)d_in[5];
    const float* W3  = (const float*)d_in[6];
    const float* b3  = (const float*)d_in[7];
    float*       out = (float*)d_out;
    const int    N = N_NODES, E = N_EDGES;

    // workspace layout (bytes) — total ~115 MB
    char*  ws      = (char*)d_ws;
    int*   flag    = (int*)ws;                          // 4 B
    int*   cnt     = (int*)(ws + 1 * (1u << 20));       // 400 KB
    int*   fillarr = (int*)(ws + 2 * (1u << 20));       // 400 KB
    float* dis     = (float*)(ws + 3 * (1u << 20));     // 400 KB
    int*   rowptr  = (int*)(ws + 4 * (1u << 20));       // 400 KB + 4
    int*   part    = (int*)(ws + 5 * (1u << 20));       // ~1.6 KB
    int*   part_ex = (int*)(ws + 5 * (1u << 20) + 65536);
    int*   es      = (int*)(ws + 6 * (1u << 20));       // 6.4 MB
    float* B1      = (float*)(ws + 13 * (size_t)(1u << 20));  // 51.2 MB
    float* B2      = (float*)(ws + 65 * (size_t)(1u << 20));  // 51.2 MB

    // ---- CSR build ----
    k_detect<<<1, 256, 0, stream>>>(ei, flag);
    hipMemsetAsync(cnt, 0, N * sizeof(int), stream);
    hipMemsetAsync(fillarr, 0, N * sizeof(int), stream);
    k_count<<<(E + 255) / 256, 256, 0, stream>>>(ei, flag, cnt, E);
    k_dis<<<(N + 255) / 256, 256, 0, stream>>>(cnt, dis, N);
    k_scan1<<<NB_SCAN, 256, 0, stream>>>(cnt, part, N);
    k_scan2<<<1, 512, 0, stream>>>(part, part_ex, NB_SCAN);
    k_scan3<<<NB_SCAN, 256, 0, stream>>>(cnt, part_ex, rowptr, N, E);
    k_fill<<<(E + 255) / 256, 256, 0, stream>>>(ei, flag, rowptr, fillarr, es, E);

    // ---- layer 1 ----
    k_gemm<32, 64, 128><<<(N + 63) / 64, 256, 0, stream>>>(x, W1, nullptr, B1, N);
    k_pull128<<<(N + 3) / 4, 256, 0, stream>>>(rowptr, es, dis, B1, b1, B2, N);

    // ---- layer 2 ----
    k_gemm<32, 64, 128><<<(N + 63) / 64, 256, 0, stream>>>(B2, W2, nullptr, B1, N);
    k_pull128<<<(N + 3) / 4, 256, 0, stream>>>(rowptr, es, dis, B1, b2, B2, N);

    // ---- layer 3 + log_softmax ----
    k_gemm<16, 128, 40><<<(N + 127) / 128, 256, 0, stream>>>(B2, W3, nullptr, B1, N);
    k_pull40_lsm<<<(N + 3) / 4, 256, 0, stream>>>(rowptr, es, dis, B1, b3, out, N);
}

// Round 3
// 582.330 us; speedup vs baseline: 5.6488x; 1.6350x over previous
//
#include <hip/hip_runtime.h>
#include <cstdint>

#define N_NODES 100000
#define N_EDGES 1600000
#define F_IN 128
#define HID 128
#define N_CLS 40
#define NB_SCAN ((N_NODES + 255) / 256)

typedef __attribute__((ext_vector_type(8))) short bf16x8;
typedef __attribute__((ext_vector_type(4))) float f32x4;

__device__ __forceinline__ unsigned short f2b(float f) {  // RNE f32->bf16
    unsigned u = __float_as_uint(f);
    return (unsigned short)((u + 0x7fffu + ((u >> 16) & 1u)) >> 16);
}
__device__ __forceinline__ float b2f(unsigned us) {
    return __uint_as_float(us << 16);
}

// ---------------------------------------------------------------------------
// Edge dtype detection (int64 vs int32 edge_index). Deterministic.
// ---------------------------------------------------------------------------
__global__ __launch_bounds__(256) void k_detect(const int* __restrict__ e, int* __restrict__ flag) {
    __shared__ int sor;
    if (threadIdx.x == 0) sor = 0;
    __syncthreads();
    atomicOr(&sor, e[threadIdx.x * 2 + 1]);
    __syncthreads();
    if (threadIdx.x == 0) flag[0] = (sor == 0) ? 1 : 0;  // 1 = int64 layout
}

__device__ __forceinline__ int edge_at(const int* e, const int* flag, int which, int i) {
    return flag[0] ? e[2 * ((size_t)which * N_EDGES + i)] : e[(size_t)which * N_EDGES + i];
}

__global__ __launch_bounds__(256) void k_count(const int* __restrict__ e, const int* __restrict__ flag,
                                               int* __restrict__ cnt, int E) {
    int i = blockIdx.x * 256 + threadIdx.x;
    if (i < E) atomicAdd(&cnt[edge_at(e, flag, 1, i)], 1);
}

__global__ __launch_bounds__(256) void k_dis(const int* __restrict__ cnt, float* __restrict__ dis, int N) {
    int i = blockIdx.x * 256 + threadIdx.x;
    if (i < N) dis[i] = rsqrtf((float)(cnt[i] + 1));
}

// ---------------- exclusive scan of cnt -> rowptr --------------------------
__global__ __launch_bounds__(256) void k_scan1(const int* __restrict__ cnt, int* __restrict__ part, int N) {
    __shared__ int s[256];
    int i = blockIdx.x * 256 + threadIdx.x;
    s[threadIdx.x] = (i < N) ? cnt[i] : 0;
    __syncthreads();
    for (int off = 128; off; off >>= 1) {
        if (threadIdx.x < off) s[threadIdx.x] += s[threadIdx.x + off];
        __syncthreads();
    }
    if (threadIdx.x == 0) part[blockIdx.x] = s[0];
}

__global__ __launch_bounds__(512) void k_scan2(const int* __restrict__ part, int* __restrict__ part_ex, int nb) {
    __shared__ int s[512];
    int t = threadIdx.x;
    s[t] = (t < nb) ? part[t] : 0;
    __syncthreads();
    for (int off = 1; off < 512; off <<= 1) {
        int v = (t >= off) ? s[t - off] : 0;
        __syncthreads();
        s[t] += v;
        __syncthreads();
    }
    if (t < nb) part_ex[t] = (t == 0) ? 0 : s[t - 1];
}

__global__ __launch_bounds__(256) void k_scan3(const int* __restrict__ cnt, const int* __restrict__ part_ex,
                                               int* __restrict__ rowptr, int N, int E) {
    __shared__ int s[256];
    int i = blockIdx.x * 256 + threadIdx.x;
    int c = (i < N) ? cnt[i] : 0;
    s[threadIdx.x] = c;
    __syncthreads();
    for (int off = 1; off < 256; off <<= 1) {
        int v = (threadIdx.x >= off) ? s[threadIdx.x - off] : 0;
        __syncthreads();
        s[threadIdx.x] += v;
        __syncthreads();
    }
    if (i < N) rowptr[i] = part_ex[blockIdx.x] + s[threadIdx.x] - c;
    if (i == 0) rowptr[N] = E;
}

__global__ __launch_bounds__(256) void k_fill(const int* __restrict__ e, const int* __restrict__ flag,
                                              const int* __restrict__ rowptr, int* __restrict__ fill,
                                              int* __restrict__ es, int E) {
    int i = blockIdx.x * 256 + threadIdx.x;
    if (i >= E) return;
    int s = edge_at(e, flag, 0, i);
    int d = edge_at(e, flag, 1, i);
    int pos = rowptr[d] + atomicAdd(&fill[d], 1);
    es[pos] = s;
}

// Wt[col][k] = bf16(W[k][col]), zero-padded to outp cols
__global__ __launch_bounds__(256) void k_wt(const float* __restrict__ W, unsigned short* __restrict__ Wt,
                                            int outc, int outp) {
    int idx = blockIdx.x * 256 + threadIdx.x;
    if (idx >= outp * 128) return;
    int col = idx >> 7, k = idx & 127;
    Wt[idx] = (col < outc) ? f2b(W[(size_t)k * outc + col]) : (unsigned short)0;
}

// ---------------------------------------------------------------------------
// MFMA bf16 GEMM: H[r][c] = sum_k X[r][k] * W[k][c].  Block = 64 rows, 4
// waves x 16 rows.  A-frag: row=lane&15, k=(lane>>4)*8+j (+kk*32).
// B-frag from Wt[col][k]: col=lane&15 (+n*16), same k.  D: col=lane&15,
// row=(lane>>4)*4+r.  LDS rows padded +8 bf16 (16B) -> 2-way bank alias, free.
// ---------------------------------------------------------------------------
template <int NT, bool IN_F32>
__global__ __launch_bounds__(256) void k_gemm_mfma(const void* __restrict__ Xv,
                                                   const unsigned short* __restrict__ Wt,
                                                   unsigned short* __restrict__ Hout, int N, int outc) {
    constexpr int OUTP = NT * 16;
    __shared__ __align__(16) unsigned short sX[64 * 136];
    __shared__ __align__(16) unsigned short sW[OUTP * 136];
    const int tid  = threadIdx.x;
    const int row0 = blockIdx.x * 64;

    if (IN_F32) {
        const float* X = (const float*)Xv;
        for (int c = tid; c < 64 * 16; c += 256) {
            int r = c >> 4, off = c & 15, row = row0 + r;
            unsigned short tmp[8];
            if (row < N) {
                const float* p = X + (size_t)row * 128 + off * 8;
#pragma unroll
                for (int j = 0; j < 8; ++j) tmp[j] = f2b(p[j]);
            } else {
#pragma unroll
                for (int j = 0; j < 8; ++j) tmp[j] = 0;
            }
            *(uint4*)(&sX[r * 136 + off * 8]) = *(uint4*)tmp;
        }
    } else {
        const unsigned short* X = (const unsigned short*)Xv;
        for (int c = tid; c < 64 * 16; c += 256) {
            int r = c >> 4, off = c & 15, row = row0 + r;
            uint4 v = make_uint4(0, 0, 0, 0);
            if (row < N) v = *(const uint4*)(X + (size_t)row * 128 + off * 8);
            *(uint4*)(&sX[r * 136 + off * 8]) = v;
        }
    }
    for (int c = tid; c < OUTP * 16; c += 256) {
        int r = c >> 4, off = c & 15;
        *(uint4*)(&sW[r * 136 + off * 8]) = *(const uint4*)(Wt + (size_t)r * 128 + off * 8);
    }
    __syncthreads();

    const int wave = tid >> 6, lane = tid & 63;
    const int l15 = lane & 15, g = lane >> 4;
    const int arow = (wave << 4) + l15;

    f32x4 acc[NT];
#pragma unroll
    for (int n = 0; n < NT; ++n) acc[n] = (f32x4){0.f, 0.f, 0.f, 0.f};

#pragma unroll
    for (int kk = 0; kk < 4; ++kk) {
        bf16x8 a = *(const bf16x8*)(&sX[arow * 136 + kk * 32 + g * 8]);
#pragma unroll
        for (int n = 0; n < NT; ++n) {
            bf16x8 b = *(const bf16x8*)(&sW[(n * 16 + l15) * 136 + kk * 32 + g * 8]);
            acc[n] = __builtin_amdgcn_mfma_f32_16x16x32_bf16(a, b, acc[n], 0, 0, 0);
        }
    }

#pragma unroll
    for (int n = 0; n < NT; ++n) {
        int col = n * 16 + l15;
        if (col < outc) {
#pragma unroll
            for (int r = 0; r < 4; ++r) {
                int row = row0 + (wave << 4) + g * 4 + r;
                if (row < N) Hout[(size_t)row * outc + col] = f2b(acc[n][r]);
            }
        }
    }
}

// ---------------------------------------------------------------------------
// CSR pull, 128 bf16 features: wave per node, lane owns 2 feats (dword
// gather), fp32 accum, self-loop+bias+relu fused, bf16 out. Unroll x2 for MLP.
// ---------------------------------------------------------------------------
__global__ __launch_bounds__(256) void k_pull128b(const int* __restrict__ rowptr, const int* __restrict__ es,
                                                  const float* __restrict__ dis,
                                                  const unsigned short* __restrict__ H,
                                                  const float* __restrict__ bias,
                                                  unsigned short* __restrict__ Out, int N) {
    int node = blockIdx.x * 4 + (threadIdx.x >> 6);
    if (node >= N) return;
    int   lane = threadIdx.x & 63;
    int   beg = rowptr[node], end = rowptr[node + 1];
    float dd  = dis[node];

    unsigned hv = *(const unsigned*)(H + (size_t)node * 128 + lane * 2);
    float d2 = dd * dd;
    float ax = d2 * b2f(hv & 0xffffu), ay = d2 * b2f(hv >> 16);

    int p = beg;
    for (; p + 1 < end; p += 2) {
        int s0 = es[p], s1 = es[p + 1];
        float    n0 = dis[s0] * dd, n1 = dis[s1] * dd;
        unsigned u0 = *(const unsigned*)(H + (size_t)s0 * 128 + lane * 2);
        unsigned u1 = *(const unsigned*)(H + (size_t)s1 * 128 + lane * 2);
        ax = fmaf(b2f(u0 & 0xffffu), n0, ax);
        ay = fmaf(b2f(u0 >> 16), n0, ay);
        ax = fmaf(b2f(u1 & 0xffffu), n1, ax);
        ay = fmaf(b2f(u1 >> 16), n1, ay);
    }
    if (p < end) {
        int s0 = es[p];
        float    n0 = dis[s0] * dd;
        unsigned u0 = *(const unsigned*)(H + (size_t)s0 * 128 + lane * 2);
        ax = fmaf(b2f(u0 & 0xffffu), n0, ax);
        ay = fmaf(b2f(u0 >> 16), n0, ay);
    }
    ax = fmaxf(ax + bias[lane * 2], 0.f);
    ay = fmaxf(ay + bias[lane * 2 + 1], 0.f);
    unsigned o = (unsigned)f2b(ax) | ((unsigned)f2b(ay) << 16);
    *(unsigned*)(Out + (size_t)node * 128 + lane * 2) = o;
}

// 40-feature bf16 pull + bias + log_softmax; wave per node.
__global__ __launch_bounds__(256) void k_pull40_lsm(const int* __restrict__ rowptr, const int* __restrict__ es,
                                                    const float* __restrict__ dis,
                                                    const unsigned short* __restrict__ H,
                                                    const float* __restrict__ bias,
                                                    float* __restrict__ out, int N) {
    int node = blockIdx.x * 4 + (threadIdx.x >> 6);
    if (node >= N) return;
    int   lane = threadIdx.x & 63;
    int   beg = rowptr[node], end = rowptr[node + 1];
    float dd  = dis[node];

    float acc = 0.f;
    if (lane < 40) acc = dd * dd * b2f(H[(size_t)node * 40 + lane]);
    int p = beg;
    for (; p + 1 < end; p += 2) {
        int s0 = es[p], s1 = es[p + 1];
        float n0 = dis[s0] * dd, n1 = dis[s1] * dd;
        if (lane < 40) {
            acc = fmaf(b2f(H[(size_t)s0 * 40 + lane]), n0, acc);
            acc = fmaf(b2f(H[(size_t)s1 * 40 + lane]), n1, acc);
        }
    }
    if (p < end) {
        int s0 = es[p];
        float n0 = dis[s0] * dd;
        if (lane < 40) acc = fmaf(b2f(H[(size_t)s0 * 40 + lane]), n0, acc);
    }
    float x = 0.f, m = -3.0e38f;
    if (lane < 40) { x = acc + bias[lane]; m = x; }
    for (int off = 32; off; off >>= 1) m = fmaxf(m, __shfl_xor(m, off));
    float sum = (lane < 40) ? __expf(x - m) : 0.f;
    for (int off = 32; off; off >>= 1) sum += __shfl_xor(sum, off);
    float ls = __logf(sum);
    if (lane < 40) out[(size_t)node * 40 + lane] = x - m - ls;
}

extern "C" void kernel_launch(void* const* d_in, const int* in_sizes, int n_in,
                              void* d_out, int out_size, void* d_ws, size_t ws_size,
                              hipStream_t stream) {
    const float* x   = (const float*)d_in[0];
    const int*   ei  = (const int*)d_in[1];
    const float* W1  = (const float*)d_in[2];
    const float* b1  = (const float*)d_in[3];
    const float* W2  = (const float*)d_in[4];
    const float* b2  = (const float*)d_in[5];
    const float* W3  = (const float*)d_in[6];
    const float* b3  = (const float*)d_in[7];
    float*       out = (float*)d_out;
    const int    N = N_NODES, E = N_EDGES;

    // workspace layout (bytes) — ~72 MB total
    char*           ws      = (char*)d_ws;
    int*            flag    = (int*)ws;
    int*            cnt     = (int*)(ws + 1 * (1u << 20));
    int*            fillarr = (int*)(ws + 2 * (1u << 20));
    float*          dis     = (float*)(ws + 3 * (1u << 20));
    int*            rowptr  = (int*)(ws + 4 * (1u << 20));
    int*            part    = (int*)(ws + 5 * (1u << 20));
    int*            part_ex = (int*)(ws + 5 * (1u << 20) + 65536);
    unsigned short* Wt1     = (unsigned short*)(ws + 5 * (1u << 20) + 131072);  // 32 KB
    unsigned short* Wt2     = Wt1 + 128 * 128;                                   // 32 KB
    unsigned short* Wt3     = Wt2 + 128 * 128;                                   // 12 KB
    int*            es      = (int*)(ws + 6 * (size_t)(1u << 20));               // 6.4 MB
    unsigned short* B1b     = (unsigned short*)(ws + 13 * (size_t)(1u << 20));   // 25.6 MB
    unsigned short* B2b     = (unsigned short*)(ws + 40 * (size_t)(1u << 20));   // 25.6 MB

    // ---- CSR build + weight prep ----
    k_detect<<<1, 256, 0, stream>>>(ei, flag);
    hipMemsetAsync(cnt, 0, N * sizeof(int), stream);
    hipMemsetAsync(fillarr, 0, N * sizeof(int), stream);
    k_count<<<(E + 255) / 256, 256, 0, stream>>>(ei, flag, cnt, E);
    k_dis<<<(N + 255) / 256, 256, 0, stream>>>(cnt, dis, N);
    k_scan1<<<NB_SCAN, 256, 0, stream>>>(cnt, part, N);
    k_scan2<<<1, 512, 0, stream>>>(part, part_ex, NB_SCAN);
    k_scan3<<<NB_SCAN, 256, 0, stream>>>(cnt, part_ex, rowptr, N, E);
    k_fill<<<(E + 255) / 256, 256, 0, stream>>>(ei, flag, rowptr, fillarr, es, E);
    k_wt<<<(128 * 128 + 255) / 256, 256, 0, stream>>>(W1, Wt1, 128, 128);
    k_wt<<<(128 * 128 + 255) / 256, 256, 0, stream>>>(W2, Wt2, 128, 128);
    k_wt<<<(48 * 128 + 255) / 256, 256, 0, stream>>>(W3, Wt3, 40, 48);

    const int gb = (N + 63) / 64;  // GEMM blocks

    // ---- layer 1 ----
    k_gemm_mfma<8, true><<<gb, 256, 0, stream>>>(x, Wt1, B1b, N, 128);
    k_pull128b<<<(N + 3) / 4, 256, 0, stream>>>(rowptr, es, dis, B1b, b1, B2b, N);

    // ---- layer 2 ----
    k_gemm_mfma<8, false><<<gb, 256, 0, stream>>>(B2b, Wt2, B1b, N, 128);
    k_pull128b<<<(N + 3) / 4, 256, 0, stream>>>(rowptr, es, dis, B1b, b2, B2b, N);

    // ---- layer 3 + log_softmax ----
    k_gemm_mfma<3, false><<<gb, 256, 0, stream>>>(B2b, Wt3, B1b, N, 40);
    k_pull40_lsm<<<(N + 3) / 4, 256, 0, stream>>>(rowptr, es, dis, B1b, b3, out, N);
}